// Round 1
// baseline (109.894 us; speedup 1.0000x reference)
//
#include <hip/hip_runtime.h>

#define GG 256
#define PP 512
#define FF 4
#define KK 6
#define NN (GG*PP)

__global__ __launch_bounds__(512) void knn_prenn_kernel(
    const float* __restrict__ x,
    const float* __restrict__ pre_W1, const float* __restrict__ pre_b1, const float* __restrict__ pre_a1,
    const float* __restrict__ pre_W2, const float* __restrict__ pre_b2, const float* __restrict__ pre_a2,
    int* __restrict__ knn_idx,      // [K][N] local neighbor idx (0..511)
    float4* __restrict__ h2out,     // [N]
    float* __restrict__ bn_part)    // [8][G] (0..3 sum, 4..7 sumsq)
{
    __shared__ float4 xs[PP];
    __shared__ float sq[PP];
    __shared__ float wred[8][8];
    const int g = blockIdx.x, p = threadIdx.x;
    const int gp = g*PP + p;

    float4 xp = ((const float4*)x)[gp];
    xs[p] = xp;
    float sqp = xp.x*xp.x + xp.y*xp.y + xp.z*xp.z + xp.w*xp.w;
    sq[p] = sqp;
    __syncthreads();

    // top-6 smallest distances, tie-break: lower index wins (matches top_k)
    float bd[KK]; int bi[KK];
#pragma unroll
    for (int j=0;j<KK;j++){ bd[j]=3.0e38f; bi[j]=0; }
    float wmax = 3.0e38f; int wslot = 0;

    for (int q=0;q<PP;q++){
        float4 xq = xs[q];
        float dot = xp.x*xq.x + xp.y*xq.y + xp.z*xq.z + xp.w*xq.w;
        float d = sqp + sq[q] - 2.0f*dot;
        if (q != p && d < wmax){
#pragma unroll
            for (int j=0;j<KK;j++) if (j==wslot){ bd[j]=d; bi[j]=q; }
            wmax = bd[0]; wslot = 0;
#pragma unroll
            for (int j=1;j<KK;j++) if (bd[j] > wmax){ wmax=bd[j]; wslot=j; }
        }
    }
#pragma unroll
    for (int j=0;j<KK;j++) knn_idx[j*NN + gp] = bi[j];

    // fused pre_nn: Linear-PReLU-Linear-PReLU
    float h1[FF], h2[FF];
#pragma unroll
    for (int fo=0;fo<FF;fo++){
        float m = xp.x*pre_W1[0*FF+fo] + xp.y*pre_W1[1*FF+fo]
                + xp.z*pre_W1[2*FF+fo] + xp.w*pre_W1[3*FF+fo] + pre_b1[fo];
        h1[fo] = m >= 0.0f ? m : pre_a1[fo]*m;
    }
#pragma unroll
    for (int fo=0;fo<FF;fo++){
        float m = h1[0]*pre_W2[0*FF+fo] + h1[1]*pre_W2[1*FF+fo]
                + h1[2]*pre_W2[2*FF+fo] + h1[3]*pre_W2[3*FF+fo] + pre_b2[fo];
        h2[fo] = m >= 0.0f ? m : pre_a2[fo]*m;
    }
    h2out[gp] = make_float4(h2[0],h2[1],h2[2],h2[3]);

    // block-partial BN stats
    float v[8];
#pragma unroll
    for (int f=0;f<4;f++){ v[f]=h2[f]; v[4+f]=h2[f]*h2[f]; }
#pragma unroll
    for (int off=32; off; off>>=1){
#pragma unroll
        for (int f=0;f<8;f++) v[f] += __shfl_down(v[f], off);
    }
    int w = p>>6;
    if ((p&63)==0){
#pragma unroll
        for (int f=0;f<8;f++) wred[w][f]=v[f];
    }
    __syncthreads();
    if (p < 8){
        float a=0;
#pragma unroll
        for (int w2=0;w2<8;w2++) a += wred[w2][p];
        bn_part[p*GG + g] = a;
    }
}

__global__ __launch_bounds__(512) void graph_kernel(
    const float4* __restrict__ h2in,
    const int* __restrict__ knn_idx,
    const float* __restrict__ bn_part,
    const float* __restrict__ bn_g, const float* __restrict__ bn_b,
    const float* __restrict__ act_a,
    const float* __restrict__ conv_Wm, const float* __restrict__ conv_bm,
    const float* __restrict__ hlv_W1, const float* __restrict__ hlv_b1,
    const float* __restrict__ hlv_W2, const float* __restrict__ hlv_b2,
    float* __restrict__ out)
{
    __shared__ float4 hbuf[PP];
    __shared__ float wred[8][4];
    __shared__ float pooled[20];
    __shared__ float stats[8];   // 0..3 mu, 4..7 invstd
    __shared__ float hid[20];
    const int g = blockIdx.x, p = threadIdx.x;
    const int gp = g*PP + p;

    // redundant per-block global BN stat reduction (2KB, L2-hot)
    if (p < 64){
        int vv = p>>3, j = p&7;
        float acc = 0.0f;
        for (int i=j;i<GG;i+=8) acc += bn_part[vv*GG + i];
        acc += __shfl_xor(acc,1); acc += __shfl_xor(acc,2); acc += __shfl_xor(acc,4);
        if (j==0) stats[vv] = acc;
    }
    __syncthreads();
    if (p < 4){
        float mu  = stats[p]   * (1.0f/NN);
        float var = stats[4+p] * (1.0f/NN) - mu*mu;
        stats[p]   = mu;
        stats[4+p] = 1.0f / sqrtf(var + 1e-5f);
    }
    __syncthreads();

    float4 h2v = h2in[gp];
    float hp[4];
    {
        float h2a[4] = {h2v.x, h2v.y, h2v.z, h2v.w};
#pragma unroll
        for (int f=0;f<4;f++)
            hp[f] = (h2a[f] - stats[f]) * stats[4+f] * bn_g[f] + bn_b[f];
    }
    hbuf[p] = make_float4(hp[0],hp[1],hp[2],hp[3]);
    int nb[KK];
#pragma unroll
    for (int j=0;j<KK;j++) nb[j] = knn_idx[j*NN + gp];

    auto block_accum = [&](const float* h, int slice){
        float v0=h[0], v1=h[1], v2=h[2], v3=h[3];
#pragma unroll
        for (int off=32; off; off>>=1){
            v0 += __shfl_down(v0,off); v1 += __shfl_down(v1,off);
            v2 += __shfl_down(v2,off); v3 += __shfl_down(v3,off);
        }
        int w = p>>6;
        if ((p&63)==0){ wred[w][0]=v0; wred[w][1]=v1; wred[w][2]=v2; wred[w][3]=v3; }
        __syncthreads();
        if (p < 4){
            float a=0;
#pragma unroll
            for (int w2=0;w2<8;w2++) a += wred[w2][p];
            pooled[slice*4+p] = a;
        }
        __syncthreads();
    };

    block_accum(hp, 0);   // syncs also publish hbuf before layer-0 gathers

#pragma unroll 1
    for (int L=0; L<4; L++){
        float4 s = make_float4(0.f,0.f,0.f,0.f);
#pragma unroll
        for (int j=0;j<KK;j++){
            float4 hn = hbuf[nb[j]];
            s.x+=hn.x; s.y+=hn.y; s.z+=hn.z; s.w+=hn.w;
        }
        const float* W  = conv_Wm + L*16;
        const float* bm = conv_bm + L*4;
        float nh[4];
#pragma unroll
        for (int fo=0;fo<4;fo++){
            float m = s.x*W[0*4+fo] + s.y*W[1*4+fo] + s.z*W[2*4+fo] + s.w*W[3*4+fo]
                    + 6.0f*bm[fo] + hp[fo];
            float a = act_a[fo];
            nh[fo] = m >= 0.0f ? m : a*m;
        }
        __syncthreads();   // all gathers of old hbuf complete
        hbuf[p] = make_float4(nh[0],nh[1],nh[2],nh[3]);
#pragma unroll
        for (int f=0;f<4;f++) hp[f]=nh[f];
        block_accum(hp, L+1);  // internal sync publishes new hbuf
    }

    // head MLP: relu(pooled @ W1 + b1) @ W2 + b2
    if (p < 20){
        float acc = hlv_b1[p];
#pragma unroll 1
        for (int k2=0;k2<20;k2++) acc += pooled[k2]*hlv_W1[k2*20+p];
        hid[p] = acc > 0.0f ? acc : 0.0f;
    }
    __syncthreads();
    if (p == 0){
        float o = hlv_b2[0];
#pragma unroll 1
        for (int j=0;j<20;j++) o += hid[j]*hlv_W2[j];
        out[g] = o;
    }
}

extern "C" void kernel_launch(void* const* d_in, const int* in_sizes, int n_in,
                              void* d_out, int out_size, void* d_ws, size_t ws_size,
                              hipStream_t stream)
{
    const float* x      = (const float*)d_in[0];
    // d_in[1] = batch (int32) — structure known, unused
    const float* pre_W1 = (const float*)d_in[2];
    const float* pre_b1 = (const float*)d_in[3];
    const float* pre_a1 = (const float*)d_in[4];
    const float* pre_W2 = (const float*)d_in[5];
    const float* pre_b2 = (const float*)d_in[6];
    const float* pre_a2 = (const float*)d_in[7];
    const float* bn_g   = (const float*)d_in[8];
    const float* bn_b   = (const float*)d_in[9];
    const float* act_a  = (const float*)d_in[10];
    const float* conv_Wm= (const float*)d_in[11];
    const float* conv_bm= (const float*)d_in[12];
    const float* hlv_W1 = (const float*)d_in[13];
    const float* hlv_b1 = (const float*)d_in[14];
    const float* hlv_W2 = (const float*)d_in[15];
    const float* hlv_b2 = (const float*)d_in[16];

    char* ws = (char*)d_ws;
    int*    knn = (int*)ws;                                            // 6*N ints = 3 MB
    float4* h2  = (float4*)(ws + (size_t)6*NN*sizeof(int));            // N float4 = 2 MB
    float*  bnp = (float*)(ws + (size_t)6*NN*sizeof(int) + (size_t)NN*sizeof(float4)); // 8*G floats

    knn_prenn_kernel<<<GG, PP, 0, stream>>>(x, pre_W1,pre_b1,pre_a1,
                                            pre_W2,pre_b2,pre_a2, knn, h2, bnp);
    graph_kernel<<<GG, PP, 0, stream>>>(h2, knn, bnp, bn_g,bn_b, act_a,
                                        conv_Wm,conv_bm, hlv_W1,hlv_b1,hlv_W2,hlv_b2,
                                        (float*)d_out);
}

// Round 2
// 65.639 us; speedup vs baseline: 1.6742x; 1.6742x over previous
//
#include <hip/hip_runtime.h>

#define GG 256
#define PP 512
#define FF 4
#define KK 6
#define NN (GG*PP)

__global__ __launch_bounds__(512) void knn_prenn_kernel(
    const float* __restrict__ x,
    const float* __restrict__ pre_W1, const float* __restrict__ pre_b1, const float* __restrict__ pre_a1,
    const float* __restrict__ pre_W2, const float* __restrict__ pre_b2, const float* __restrict__ pre_a2,
    int* __restrict__ knn_idx,      // [K][N] local neighbor idx (0..511)
    float4* __restrict__ h2out,     // [N]
    float* __restrict__ bn_part)    // [8][G] (0..3 sum, 4..7 sumsq)
{
    __shared__ float4 xs[PP];    // -2*x per node
    __shared__ float  sqs[PP];   // |x|^2 per node
    __shared__ float  wred[8][8];
    const int t = threadIdx.x;
    const int bid = blockIdx.x;
    const int g = bid >> 1, bsub = bid & 1;   // 2 blocks per graph
    const int gbase = g * PP;

    // stage graph nodes: -2*x and |x|^2
    float4 xt = ((const float4*)x)[gbase + t];
    xs[t] = make_float4(-2.0f*xt.x, -2.0f*xt.y, -2.0f*xt.z, -2.0f*xt.w);
    sqs[t] = xt.x*xt.x + xt.y*xt.y + xt.z*xt.z + xt.w*xt.w;

    if (bsub == 0) {
        // fused pre_nn for node t
        float h1[FF], h2[FF];
#pragma unroll
        for (int fo=0;fo<FF;fo++){
            float m = xt.x*pre_W1[0*FF+fo] + xt.y*pre_W1[1*FF+fo]
                    + xt.z*pre_W1[2*FF+fo] + xt.w*pre_W1[3*FF+fo] + pre_b1[fo];
            h1[fo] = m >= 0.0f ? m : pre_a1[fo]*m;
        }
#pragma unroll
        for (int fo=0;fo<FF;fo++){
            float m = h1[0]*pre_W2[0*FF+fo] + h1[1]*pre_W2[1*FF+fo]
                    + h1[2]*pre_W2[2*FF+fo] + h1[3]*pre_W2[3*FF+fo] + pre_b2[fo];
            h2[fo] = m >= 0.0f ? m : pre_a2[fo]*m;
        }
        h2out[gbase + t] = make_float4(h2[0],h2[1],h2[2],h2[3]);

        float v[8];
#pragma unroll
        for (int f=0;f<4;f++){ v[f]=h2[f]; v[4+f]=h2[f]*h2[f]; }
#pragma unroll
        for (int off=32; off; off>>=1){
#pragma unroll
            for (int f=0;f<8;f++) v[f] += __shfl_down(v[f], off);
        }
        int w = t>>6;
        if ((t&63)==0){
#pragma unroll
            for (int f=0;f<8;f++) wred[w][f]=v[f];
        }
    }
    __syncthreads();   // publishes xs/sqs AND wred
    if (bsub == 0 && t < 8){
        float a=0;
#pragma unroll
        for (int w2=0;w2<8;w2++) a += wred[w2][t];
        bn_part[t*GG + g] = a;
    }

    // ---- scan: 2 scanners per target, 256 candidates each ----
    const int s = t & 1;
    const int p = bsub*256 + (t >> 1);            // local target node
    float4 xp = ((const float4*)x)[gbase + p];    // raw target coords

    // top-6 in shifted space (true d = acc + |x_p|^2), sorted DESC: bd[0] = max
    float bd[KK]; int bi[KK];
#pragma unroll
    for (int j=0;j<KK;j++){ bd[j] = 3.0e38f; bi[j] = 0; }
    float pd = 0.0f; int pq = -1;                 // 1-slot pending buffer

#define CASCADE(dv, qv)                                                     \
    {                                                                       \
        bool c1 = dv < bd[1]; bool c2 = dv < bd[2]; bool c3 = dv < bd[3];   \
        bool c4 = dv < bd[4]; bool c5 = dv < bd[5];                         \
        bd[0] = c1 ? bd[1] : dv;                 bi[0] = c1 ? bi[1] : qv;   \
        bd[1] = c2 ? bd[2] : (c1 ? dv : bd[1]);  bi[1] = c2 ? bi[2] : (c1 ? qv : bi[1]); \
        bd[2] = c3 ? bd[3] : (c2 ? dv : bd[2]);  bi[2] = c3 ? bi[3] : (c2 ? qv : bi[2]); \
        bd[3] = c4 ? bd[4] : (c3 ? dv : bd[3]);  bi[3] = c4 ? bi[4] : (c3 ? qv : bi[3]); \
        bd[4] = c5 ? bd[5] : (c4 ? dv : bd[4]);  bi[4] = c5 ? bi[5] : (c4 ? qv : bi[4]); \
        bd[5] = c5 ? dv : bd[5];                 bi[5] = c5 ? qv : bi[5];   \
    }

    const int qbase = s * 256;
#pragma unroll 1
    for (int i=0;i<256;i++){
        int q = qbase + i;
        float4 m = xs[q];
        float acc = fmaf(m.x, xp.x, fmaf(m.y, xp.y, fmaf(m.z, xp.z, fmaf(m.w, xp.w, sqs[q]))));
        bool pass = (acc < bd[0]) && (q != p);
        if (__any(pass && (pq >= 0))) {
            if (pq >= 0 && pd < bd[0]) CASCADE(pd, pq);
            pq = -1;
        }
        if (pass) { pd = acc; pq = q; }
    }
    if (pq >= 0 && pd < bd[0]) CASCADE(pd, pq);

    // ---- merge the two scanners' sorted-desc lists: 6 smallest of union ----
    float od[KK]; int oi[KK];
#pragma unroll
    for (int j=0;j<KK;j++){ od[j] = __shfl_xor(bd[j], 1); oi[j] = __shfl_xor(bi[j], 1); }
    bool pref = (s == 1);   // on exact tie prefer scanner 0 (lower q range)
    int ni[KK];
#pragma unroll
    for (int j=0;j<KK;j++){
        float mv = bd[5-j];
        bool take = (od[j] < mv) || (pref && (od[j] == mv));
        ni[j] = take ? oi[j] : bi[5-j];
    }
    if (s == 0){
#pragma unroll
        for (int j=0;j<KK;j++) knn_idx[j*NN + gbase + p] = ni[j];
    }
}

__global__ __launch_bounds__(512) void graph_kernel(
    const float4* __restrict__ h2in,
    const int* __restrict__ knn_idx,
    const float* __restrict__ bn_part,
    const float* __restrict__ bn_g, const float* __restrict__ bn_b,
    const float* __restrict__ act_a,
    const float* __restrict__ conv_Wm, const float* __restrict__ conv_bm,
    const float* __restrict__ hlv_W1, const float* __restrict__ hlv_b1,
    const float* __restrict__ hlv_W2, const float* __restrict__ hlv_b2,
    float* __restrict__ out)
{
    __shared__ float4 hbuf[PP];
    __shared__ float wred[8][4];
    __shared__ float pooled[20];
    __shared__ float stats[8];   // 0..3 mu, 4..7 invstd
    __shared__ float hid[20];
    const int g = blockIdx.x, p = threadIdx.x;
    const int gp = g*PP + p;

    // redundant per-block global BN stat reduction (2KB, L2-hot)
    if (p < 64){
        int vv = p>>3, j = p&7;
        float acc = 0.0f;
        for (int i=j;i<GG;i+=8) acc += bn_part[vv*GG + i];
        acc += __shfl_xor(acc,1); acc += __shfl_xor(acc,2); acc += __shfl_xor(acc,4);
        if (j==0) stats[vv] = acc;
    }
    __syncthreads();
    if (p < 4){
        float mu  = stats[p]   * (1.0f/NN);
        float var = stats[4+p] * (1.0f/NN) - mu*mu;
        stats[p]   = mu;
        stats[4+p] = 1.0f / sqrtf(var + 1e-5f);
    }
    __syncthreads();

    float4 h2v = h2in[gp];
    float hp[4];
    {
        float h2a[4] = {h2v.x, h2v.y, h2v.z, h2v.w};
#pragma unroll
        for (int f=0;f<4;f++)
            hp[f] = (h2a[f] - stats[f]) * stats[4+f] * bn_g[f] + bn_b[f];
    }
    hbuf[p] = make_float4(hp[0],hp[1],hp[2],hp[3]);
    int nb[KK];
#pragma unroll
    for (int j=0;j<KK;j++) nb[j] = knn_idx[j*NN + gp];

    auto block_accum = [&](const float* h, int slice){
        float v0=h[0], v1=h[1], v2=h[2], v3=h[3];
#pragma unroll
        for (int off=32; off; off>>=1){
            v0 += __shfl_down(v0,off); v1 += __shfl_down(v1,off);
            v2 += __shfl_down(v2,off); v3 += __shfl_down(v3,off);
        }
        int w = p>>6;
        if ((p&63)==0){ wred[w][0]=v0; wred[w][1]=v1; wred[w][2]=v2; wred[w][3]=v3; }
        __syncthreads();
        if (p < 4){
            float a=0;
#pragma unroll
            for (int w2=0;w2<8;w2++) a += wred[w2][p];
            pooled[slice*4+p] = a;
        }
        __syncthreads();
    };

    block_accum(hp, 0);   // syncs also publish hbuf before layer-0 gathers

#pragma unroll 1
    for (int L=0; L<4; L++){
        float4 sm = make_float4(0.f,0.f,0.f,0.f);
#pragma unroll
        for (int j=0;j<KK;j++){
            float4 hn = hbuf[nb[j]];
            sm.x+=hn.x; sm.y+=hn.y; sm.z+=hn.z; sm.w+=hn.w;
        }
        const float* W  = conv_Wm + L*16;
        const float* bm = conv_bm + L*4;
        float nh[4];
#pragma unroll
        for (int fo=0;fo<4;fo++){
            float m = sm.x*W[0*4+fo] + sm.y*W[1*4+fo] + sm.z*W[2*4+fo] + sm.w*W[3*4+fo]
                    + 6.0f*bm[fo] + hp[fo];
            float a = act_a[fo];
            nh[fo] = m >= 0.0f ? m : a*m;
        }
        __syncthreads();   // all gathers of old hbuf complete
        hbuf[p] = make_float4(nh[0],nh[1],nh[2],nh[3]);
#pragma unroll
        for (int f=0;f<4;f++) hp[f]=nh[f];
        block_accum(hp, L+1);  // internal sync publishes new hbuf
    }

    // head MLP: relu(pooled @ W1 + b1) @ W2 + b2
    if (p < 20){
        float acc = hlv_b1[p];
#pragma unroll 1
        for (int k2=0;k2<20;k2++) acc += pooled[k2]*hlv_W1[k2*20+p];
        hid[p] = acc > 0.0f ? acc : 0.0f;
    }
    __syncthreads();
    if (p == 0){
        float o = hlv_b2[0];
#pragma unroll 1
        for (int j=0;j<20;j++) o += hid[j]*hlv_W2[j];
        out[g] = o;
    }
}

extern "C" void kernel_launch(void* const* d_in, const int* in_sizes, int n_in,
                              void* d_out, int out_size, void* d_ws, size_t ws_size,
                              hipStream_t stream)
{
    const float* x      = (const float*)d_in[0];
    const float* pre_W1 = (const float*)d_in[2];
    const float* pre_b1 = (const float*)d_in[3];
    const float* pre_a1 = (const float*)d_in[4];
    const float* pre_W2 = (const float*)d_in[5];
    const float* pre_b2 = (const float*)d_in[6];
    const float* pre_a2 = (const float*)d_in[7];
    const float* bn_g   = (const float*)d_in[8];
    const float* bn_b   = (const float*)d_in[9];
    const float* act_a  = (const float*)d_in[10];
    const float* conv_Wm= (const float*)d_in[11];
    const float* conv_bm= (const float*)d_in[12];
    const float* hlv_W1 = (const float*)d_in[13];
    const float* hlv_b1 = (const float*)d_in[14];
    const float* hlv_W2 = (const float*)d_in[15];
    const float* hlv_b2 = (const float*)d_in[16];

    char* ws = (char*)d_ws;
    int*    knn = (int*)ws;                                            // 6*N ints = 3 MB
    float4* h2  = (float4*)(ws + (size_t)6*NN*sizeof(int));            // N float4 = 2 MB
    float*  bnp = (float*)(ws + (size_t)6*NN*sizeof(int) + (size_t)NN*sizeof(float4)); // 8*G floats

    knn_prenn_kernel<<<GG*2, PP, 0, stream>>>(x, pre_W1,pre_b1,pre_a1,
                                              pre_W2,pre_b2,pre_a2, knn, h2, bnp);
    graph_kernel<<<GG, PP, 0, stream>>>(h2, knn, bnp, bn_g,bn_b, act_a,
                                        conv_Wm,conv_bm, hlv_W1,hlv_b1,hlv_W2,hlv_b2,
                                        (float*)d_out);
}